// Round 1
// baseline (231.458 us; speedup 1.0000x reference)
//
#include <hip/hip_runtime.h>
#include <hip/hip_bf16.h>
#include <stdint.h>

// ---------------------------------------------------------------------------
// MSA: z[4,2048,768] fp32, W_qkv[2304,768] fp32 -> out[4,2048,768] fp32
// Pass 1: QKV GEMM (bf16 MFMA, fp32 accum), scatter to Q/K/V [48][2048][64] bf16
//         Q pre-scaled by 0.125*log2(e) (softmax runs in exp2 domain)
// Pass 2: flash attention per (head, 128-q-rows) block, swapped QK^T layout
// ---------------------------------------------------------------------------

typedef __attribute__((ext_vector_type(8))) short bf8_t;   // 8 x bf16 (4 VGPR)
typedef __attribute__((ext_vector_type(4))) float f4_t;    // MFMA accum

__device__ __forceinline__ unsigned short f2bf(float f) {
  union { float f; unsigned u; } x; x.f = f;
  return (unsigned short)((x.u + 0x7fffu + ((x.u >> 16) & 1u)) >> 16);  // RNE
}
__device__ __forceinline__ float bf2f(unsigned short b) {
  union { float f; unsigned u; } x; x.u = ((unsigned)b) << 16;
  return x.f;
}

// ---------------------------------------------------------------------------
// Kernel 1: C[8192,2304] = Z[8192,768] @ W[2304,768]^T  (both K-contiguous)
// 128x128 tile, BK=64, 256 thr = 4 waves (2x2), each wave 64x64 via 4x4 frags
// LDS tiles [128][64] bf16, 16B-chunk XOR swizzle (chunk ^= row&7)
// ---------------------------------------------------------------------------
__global__ __launch_bounds__(256, 2) void qkv_gemm_kernel(
    const float* __restrict__ Z, const float* __restrict__ W,
    unsigned short* __restrict__ qb, unsigned short* __restrict__ kb,
    unsigned short* __restrict__ vb)
{
  __shared__ __align__(16) unsigned short As[128 * 64];
  __shared__ __align__(16) unsigned short Bs[128 * 64];

  const int tid = threadIdx.x;
  const int w    = tid >> 6;
  const int lane = tid & 63;
  const int g    = lane >> 4;
  const int l15  = lane & 15;
  const int m0 = blockIdx.y * 128;
  const int n0 = blockIdx.x * 128;
  const int wr = w >> 1, wc = w & 1;

  const f4_t zf = {0.f, 0.f, 0.f, 0.f};
  f4_t acc[4][4];
#pragma unroll
  for (int m = 0; m < 4; ++m)
#pragma unroll
    for (int n = 0; n < 4; ++n) acc[m][n] = zf;

  for (int k0 = 0; k0 < 768; k0 += 64) {
    __syncthreads();
    // stage A and B tiles: 1024 chunks of 8 bf16 each; fp32->bf16 fused
#pragma unroll
    for (int i = 0; i < 4; ++i) {
      const int q   = i * 256 + tid;
      const int row = q >> 3, c = q & 7;
      const int dst = row * 64 + ((c ^ (row & 7)) * 8);
      {
        const float* s = Z + (size_t)(m0 + row) * 768 + k0 + c * 8;
        float4 a0 = *(const float4*)s;
        float4 a1 = *(const float4*)(s + 4);
        union { bf8_t v; unsigned short u[8]; } pk;
        pk.u[0] = f2bf(a0.x); pk.u[1] = f2bf(a0.y); pk.u[2] = f2bf(a0.z); pk.u[3] = f2bf(a0.w);
        pk.u[4] = f2bf(a1.x); pk.u[5] = f2bf(a1.y); pk.u[6] = f2bf(a1.z); pk.u[7] = f2bf(a1.w);
        *(bf8_t*)(As + dst) = pk.v;
      }
      {
        const float* s = W + (size_t)(n0 + row) * 768 + k0 + c * 8;
        float4 a0 = *(const float4*)s;
        float4 a1 = *(const float4*)(s + 4);
        union { bf8_t v; unsigned short u[8]; } pk;
        pk.u[0] = f2bf(a0.x); pk.u[1] = f2bf(a0.y); pk.u[2] = f2bf(a0.z); pk.u[3] = f2bf(a0.w);
        pk.u[4] = f2bf(a1.x); pk.u[5] = f2bf(a1.y); pk.u[6] = f2bf(a1.z); pk.u[7] = f2bf(a1.w);
        *(bf8_t*)(Bs + dst) = pk.v;
      }
    }
    __syncthreads();

#pragma unroll
    for (int s = 0; s < 2; ++s) {
      bf8_t af[4], bfr[4];
#pragma unroll
      for (int m = 0; m < 4; ++m) {
        const int row = wr * 64 + m * 16 + l15;
        af[m] = *(const bf8_t*)(As + row * 64 + (((s * 4 + g) ^ (row & 7)) * 8));
      }
#pragma unroll
      for (int n = 0; n < 4; ++n) {
        const int row = wc * 64 + n * 16 + l15;
        bfr[n] = *(const bf8_t*)(Bs + row * 64 + (((s * 4 + g) ^ (row & 7)) * 8));
      }
#pragma unroll
      for (int m = 0; m < 4; ++m)
#pragma unroll
        for (int n = 0; n < 4; ++n)
          acc[m][n] = __builtin_amdgcn_mfma_f32_16x16x32_bf16(af[m], bfr[n], acc[m][n], 0, 0, 0);
    }
  }

  // Epilogue: D row (token) = g*4+j, col (e) = l15 within each 16x16 frag.
  const float QSCALE = 0.18033688011112042f;  // (1/sqrt(64)) * log2(e)
#pragma unroll
  for (int m = 0; m < 4; ++m) {
    const int gi = m0 + wr * 64 + m * 16 + g * 4;
#pragma unroll
    for (int n = 0; n < 4; ++n) {
      const int e   = n0 + wc * 64 + n * 16 + l15;
      const int h   = e / 192;
      const int rem = e - h * 192;
      const int mm  = rem >> 6;       // 0=q 1=k 2=v
      const int dh  = rem & 63;
      unsigned short* buf = (mm == 0) ? qb : ((mm == 1) ? kb : vb);
      const float sc = (mm == 0) ? QSCALE : 1.0f;
#pragma unroll
      for (int j = 0; j < 4; ++j) {
        const int tokg = gi + j;
        const int b    = tokg >> 11;
        const int tok  = tokg & 2047;
        buf[((size_t)((b * 12 + h) * 2048 + tok)) * 64 + dh] = f2bf(acc[m][n][j] * sc);
      }
    }
  }
}

// ---------------------------------------------------------------------------
// Kernel 2: attention. 768 blocks = 48 heads x 16 q-tiles (128 rows).
// 4 waves x 32 q-rows. KV tiles of 64. Swapped QK^T: S^T = mfma(A=K, B=Q)
// -> lane holds q = lane&15 (col), kv = kf*16 + g*4 + j (row).
// ---------------------------------------------------------------------------
__global__ __launch_bounds__(256, 2) void attn_kernel(
    const unsigned short* __restrict__ qb, const unsigned short* __restrict__ kb,
    const unsigned short* __restrict__ vb, float* __restrict__ out)
{
  __shared__ __align__(16) unsigned short Ks[64 * 64];       // [kv][dh], swizzled
  __shared__ __align__(16) unsigned short Vs[64 * 64];       // [dh][kv], swizzled
  __shared__ __align__(16) unsigned short Ps[4][32 * 72];    // per-wave [q][k], pad 72

  const int bid = blockIdx.x;
  const int nb  = (bid & 7) * 96 + (bid >> 3);   // XCD chunk swizzle (768%8==0)
  const int bh  = nb >> 4;
  const int qt  = nb & 15;
  const int tid = threadIdx.x;
  const int w    = tid >> 6;
  const int lane = tid & 63;
  const int g    = lane >> 4;
  const int l15  = lane & 15;

  const unsigned short* Qh = qb + (size_t)bh * 2048 * 64;
  const unsigned short* Kh = kb + (size_t)bh * 2048 * 64;
  const unsigned short* Vh = vb + (size_t)bh * 2048 * 64;

  const int qbase = qt * 128 + w * 32;

  // Q as B-operand: col q = l15, k(dh) = s*32 + g*8 + i (contiguous in memory)
  bf8_t qfr[2][2];
#pragma unroll
  for (int qq = 0; qq < 2; ++qq)
#pragma unroll
    for (int s = 0; s < 2; ++s)
      qfr[qq][s] = *(const bf8_t*)(Qh + (size_t)(qbase + qq * 16 + l15) * 64 + s * 32 + g * 8);

  float mrow[2] = {-1e30f, -1e30f};
  float lsum[2] = {0.f, 0.f};
  const f4_t zf = {0.f, 0.f, 0.f, 0.f};
  f4_t accO[2][4];
#pragma unroll
  for (int qq = 0; qq < 2; ++qq)
#pragma unroll
    for (int nf = 0; nf < 4; ++nf) accO[qq][nf] = zf;

  for (int t = 0; t < 32; ++t) {
    const unsigned short* Kt = Kh + t * 64 * 64;
    const unsigned short* Vt = Vh + t * 64 * 64;
    __syncthreads();   // previous tile's compute done before overwrite
#pragma unroll
    for (int i = 0; i < 2; ++i) {
      const int q   = i * 256 + tid;
      const int row = q >> 3, c = q & 7;
      // K: straight copy with chunk swizzle
      bf8_t kx = *(const bf8_t*)(Kt + row * 64 + c * 8);
      *(bf8_t*)(Ks + row * 64 + ((c ^ (row & 7)) * 8)) = kx;
      // V: transpose into Vs[dh][kv], swizzled on kv-chunks
      union { bf8_t v; unsigned short u[8]; } vv;
      vv.v = *(const bf8_t*)(Vt + row * 64 + c * 8);
      const int d0 = c * 8;
      const int kvc = row >> 3, kvo = row & 7;
#pragma unroll
      for (int x = 0; x < 8; ++x) {
        const int d = d0 + x;
        Vs[d * 64 + ((kvc ^ (d & 7)) * 8) + kvo] = vv.u[x];
      }
    }
    __syncthreads();

    // ---- S^T = K . Q^T ----
    bf8_t ka[4][2];
#pragma unroll
    for (int kf = 0; kf < 4; ++kf)
#pragma unroll
      for (int s = 0; s < 2; ++s) {
        const int row = kf * 16 + l15;
        ka[kf][s] = *(const bf8_t*)(Ks + row * 64 + (((s * 4 + g) ^ (row & 7)) * 8));
      }
    f4_t accS[4][2];
#pragma unroll
    for (int kf = 0; kf < 4; ++kf)
#pragma unroll
      for (int qq = 0; qq < 2; ++qq) {
        f4_t a = zf;
        a = __builtin_amdgcn_mfma_f32_16x16x32_bf16(ka[kf][0], qfr[qq][0], a, 0, 0, 0);
        a = __builtin_amdgcn_mfma_f32_16x16x32_bf16(ka[kf][1], qfr[qq][1], a, 0, 0, 0);
        accS[kf][qq] = a;
      }

    // ---- online softmax (scores already in log2 units) ----
    float alpha[2];
#pragma unroll
    for (int qq = 0; qq < 2; ++qq) {
      float rmax = -1e30f;
#pragma unroll
      for (int kf = 0; kf < 4; ++kf)
#pragma unroll
        for (int j = 0; j < 4; ++j) rmax = fmaxf(rmax, accS[kf][qq][j]);
      rmax = fmaxf(rmax, __shfl_xor(rmax, 16));
      rmax = fmaxf(rmax, __shfl_xor(rmax, 32));
      const float mnew = fmaxf(mrow[qq], rmax);
      alpha[qq] = exp2f(mrow[qq] - mnew);
      mrow[qq]  = mnew;

      float ps = 0.f;
      unsigned short* pw = &Ps[w][(qq * 16 + l15) * 72];
#pragma unroll
      for (int kf = 0; kf < 4; ++kf) {
        const unsigned short b0 = f2bf(exp2f(accS[kf][qq][0] - mnew));
        const unsigned short b1 = f2bf(exp2f(accS[kf][qq][1] - mnew));
        const unsigned short b2 = f2bf(exp2f(accS[kf][qq][2] - mnew));
        const unsigned short b3 = f2bf(exp2f(accS[kf][qq][3] - mnew));
        ps += bf2f(b0) + bf2f(b1) + bf2f(b2) + bf2f(b3);  // denom matches bf16 P
        *(unsigned*)(pw + kf * 16 + g * 4)     = (unsigned)b0 | ((unsigned)b1 << 16);
        *(unsigned*)(pw + kf * 16 + g * 4 + 2) = (unsigned)b2 | ((unsigned)b3 << 16);
      }
      ps += __shfl_xor(ps, 16);
      ps += __shfl_xor(ps, 32);
      lsum[qq] = lsum[qq] * alpha[qq] + ps;
    }

    // ---- rescale O (accO rows are q = g*4+j: fetch alpha cross-lane) ----
#pragma unroll
    for (int qq = 0; qq < 2; ++qq) {
      f4_t av;
#pragma unroll
      for (int j = 0; j < 4; ++j) av[j] = __shfl(alpha[qq], g * 4 + j);
#pragma unroll
      for (int nf = 0; nf < 4; ++nf) accO[qq][nf] *= av;
    }

    // ---- PV: A = P (row q = l15, k contiguous), B = V^T from Vs ----
    bf8_t pa[2][2];
#pragma unroll
    for (int qq = 0; qq < 2; ++qq)
#pragma unroll
      for (int kk = 0; kk < 2; ++kk)
        pa[qq][kk] = *(const bf8_t*)(&Ps[w][(qq * 16 + l15) * 72 + kk * 32 + g * 8]);
#pragma unroll
    for (int kk = 0; kk < 2; ++kk)
#pragma unroll
      for (int nf = 0; nf < 4; ++nf) {
        const int d = nf * 16 + l15;
        bf8_t vfr = *(const bf8_t*)(Vs + d * 64 + (((kk * 4 + g) ^ (d & 7)) * 8));
#pragma unroll
        for (int qq = 0; qq < 2; ++qq)
          accO[qq][nf] = __builtin_amdgcn_mfma_f32_16x16x32_bf16(pa[qq][kk], vfr, accO[qq][nf], 0, 0, 0);
      }
  }

  // ---- finalize: /= lsum, write out[b, n, h*64+d] fp32 ----
  const int b = bh / 12, h = bh - (bh / 12) * 12;
#pragma unroll
  for (int qq = 0; qq < 2; ++qq) {
    const float rl = 1.0f / lsum[qq];
    f4_t lv;
#pragma unroll
    for (int j = 0; j < 4; ++j) lv[j] = __shfl(rl, g * 4 + j);
#pragma unroll
    for (int nf = 0; nf < 4; ++nf) {
#pragma unroll
      for (int j = 0; j < 4; ++j) {
        const int qrow = qbase + qq * 16 + g * 4 + j;
        out[((size_t)(b * 2048 + qrow)) * 768 + h * 64 + nf * 16 + l15] = accO[qq][nf][j] * lv[j];
      }
    }
  }
}

// ---------------------------------------------------------------------------
extern "C" void kernel_launch(void* const* d_in, const int* in_sizes, int n_in,
                              void* d_out, int out_size, void* d_ws, size_t ws_size,
                              hipStream_t stream) {
  (void)in_sizes; (void)n_in; (void)out_size; (void)ws_size;
  const float* Z = (const float*)d_in[0];
  const float* W = (const float*)d_in[1];
  float* out = (float*)d_out;

  unsigned short* qb = (unsigned short*)d_ws;                    // 48*2048*64 bf16
  unsigned short* kb = qb + (size_t)48 * 2048 * 64;
  unsigned short* vb = kb + (size_t)48 * 2048 * 64;              // total 37.75 MB

  qkv_gemm_kernel<<<dim3(18, 64), 256, 0, stream>>>(Z, W, qb, kb, vb);
  attn_kernel<<<dim3(768), 256, 0, stream>>>(qb, kb, vb, out);
}

// Round 2
// 136.333 us; speedup vs baseline: 1.6977x; 1.6977x over previous
//
#include <hip/hip_runtime.h>
#include <hip/hip_bf16.h>
#include <stdint.h>

// ---------------------------------------------------------------------------
// MSA: z[4,2048,768] fp32, W_qkv[2304,768] fp32 -> out[4,2048,768] fp32
// Pass 1: QKV GEMM (bf16 MFMA, fp32 accum) -> Q,K [48][2048][64] bf16,
//         V stored TRANSPOSED [48][64][2048] bf16 (attn stages it directly).
//         Q pre-scaled by 0.125*log2(e) (softmax in exp2 domain).
// Pass 2: flash attention, dbuf LDS, 1 barrier/tile, T13 defer-max, cvt_pk.
// ---------------------------------------------------------------------------

typedef __attribute__((ext_vector_type(8))) short bf8_t;   // 8 x bf16
typedef __attribute__((ext_vector_type(4))) float f4_t;    // MFMA accum

__device__ __forceinline__ unsigned short f2bf(float f) {
  union { float f; unsigned u; } x; x.f = f;
  return (unsigned short)((x.u + 0x7fffu + ((x.u >> 16) & 1u)) >> 16);  // RNE
}
__device__ __forceinline__ unsigned cvt_pk_bf16(float lo, float hi) {
  unsigned r;
  asm("v_cvt_pk_bf16_f32 %0, %1, %2" : "=v"(r) : "v"(lo), "v"(hi));
  return r;
}

// ---------------------------------------------------------------------------
// Kernel 1: C[8192,2304] = Z[8192,768] @ W[2304,768]^T
// ---------------------------------------------------------------------------
__global__ __launch_bounds__(256, 2) void qkv_gemm_kernel(
    const float* __restrict__ Z, const float* __restrict__ W,
    unsigned short* __restrict__ qb, unsigned short* __restrict__ kb,
    unsigned short* __restrict__ vt)
{
  __shared__ __align__(16) unsigned short As[128 * 64];
  __shared__ __align__(16) unsigned short Bs[128 * 64];

  const int tid = threadIdx.x;
  const int w    = tid >> 6;
  const int lane = tid & 63;
  const int g    = lane >> 4;
  const int l15  = lane & 15;
  // XCD-bijective swizzle over flattened grid (1152 % 8 == 0)
  const int bid0 = blockIdx.y * 18 + blockIdx.x;
  const int bid  = (bid0 & 7) * 144 + (bid0 >> 3);
  const int m0 = (bid / 18) * 128;
  const int n0 = (bid % 18) * 128;
  const int wr = w >> 1, wc = w & 1;

  const f4_t zf = {0.f, 0.f, 0.f, 0.f};
  f4_t acc[4][4];
#pragma unroll
  for (int m = 0; m < 4; ++m)
#pragma unroll
    for (int n = 0; n < 4; ++n) acc[m][n] = zf;

  for (int k0 = 0; k0 < 768; k0 += 64) {
    __syncthreads();
#pragma unroll
    for (int i = 0; i < 4; ++i) {
      const int q   = i * 256 + tid;
      const int row = q >> 3, c = q & 7;
      const int dst = row * 64 + ((c ^ (row & 7)) * 8);
      {
        const float* s = Z + (size_t)(m0 + row) * 768 + k0 + c * 8;
        const float4 a0 = *(const float4*)s;
        const float4 a1 = *(const float4*)(s + 4);
        uint4 pk = { cvt_pk_bf16(a0.x, a0.y), cvt_pk_bf16(a0.z, a0.w),
                     cvt_pk_bf16(a1.x, a1.y), cvt_pk_bf16(a1.z, a1.w) };
        *(uint4*)(As + dst) = pk;
      }
      {
        const float* s = W + (size_t)(n0 + row) * 768 + k0 + c * 8;
        const float4 a0 = *(const float4*)s;
        const float4 a1 = *(const float4*)(s + 4);
        uint4 pk = { cvt_pk_bf16(a0.x, a0.y), cvt_pk_bf16(a0.z, a0.w),
                     cvt_pk_bf16(a1.x, a1.y), cvt_pk_bf16(a1.z, a1.w) };
        *(uint4*)(Bs + dst) = pk;
      }
    }
    __syncthreads();

#pragma unroll
    for (int s = 0; s < 2; ++s) {
      bf8_t af[4], bfr[4];
#pragma unroll
      for (int m = 0; m < 4; ++m) {
        const int row = wr * 64 + m * 16 + l15;
        af[m] = *(const bf8_t*)(As + row * 64 + (((s * 4 + g) ^ (row & 7)) * 8));
      }
#pragma unroll
      for (int n = 0; n < 4; ++n) {
        const int row = wc * 64 + n * 16 + l15;
        bfr[n] = *(const bf8_t*)(Bs + row * 64 + (((s * 4 + g) ^ (row & 7)) * 8));
      }
      __builtin_amdgcn_s_setprio(1);
#pragma unroll
      for (int m = 0; m < 4; ++m)
#pragma unroll
        for (int n = 0; n < 4; ++n)
          acc[m][n] = __builtin_amdgcn_mfma_f32_16x16x32_bf16(af[m], bfr[n], acc[m][n], 0, 0, 0);
      __builtin_amdgcn_s_setprio(0);
    }
  }

  // Epilogue. Frag: token = gi + j (j=0..3 consecutive), col e = e0 + l15.
  // mm/h are uniform per n-frag (16 | 64 | 192 boundaries).
  const float QSCALE = 0.18033688011112042f;  // (1/sqrt(64)) * log2(e)
#pragma unroll
  for (int m = 0; m < 4; ++m) {
    const int gi  = m0 + wr * 64 + m * 16 + g * 4;
    const int b   = gi >> 11;
    const int tok = gi & 2047;
#pragma unroll
    for (int n = 0; n < 4; ++n) {
      const int e0  = n0 + wc * 64 + n * 16;
      const int h   = e0 / 192;
      const int rem = e0 - h * 192;
      const int mm  = rem >> 6;       // 0=q 1=k 2=v
      const int dh  = (rem & 63) + l15;
      if (mm == 2) {
        // V^T [48][64][2048]: 4 consecutive tokens -> one 8B store
        uint2 pk = { cvt_pk_bf16(acc[m][n][0], acc[m][n][1]),
                     cvt_pk_bf16(acc[m][n][2], acc[m][n][3]) };
        *(uint2*)(vt + ((size_t)((b * 12 + h) * 64 + dh)) * 2048 + tok) = pk;
      } else {
        unsigned short* buf = mm ? kb : qb;
        const float sc = mm ? 1.0f : QSCALE;
        const size_t base = ((size_t)((b * 12 + h) * 2048 + tok)) * 64 + dh;
#pragma unroll
        for (int j = 0; j < 4; ++j)
          buf[base + (size_t)j * 64] = f2bf(acc[m][n][j] * sc);
      }
    }
  }
}

// ---------------------------------------------------------------------------
// Kernel 2: attention. 768 blocks = 48 heads x 16 q-tiles. 4 waves x 32 rows.
// Swapped QK^T (S^T = mfma(K, Q)); dbuf K/V LDS; 1 barrier/tile.
// ---------------------------------------------------------------------------
__global__ __launch_bounds__(256, 3) void attn_kernel(
    const unsigned short* __restrict__ qb, const unsigned short* __restrict__ kb,
    const unsigned short* __restrict__ vt, float* __restrict__ out)
{
  __shared__ __align__(16) unsigned short Ks[2][64 * 64];
  __shared__ __align__(16) unsigned short Vs[2][64 * 64];    // [dh][kv]
  __shared__ __align__(16) unsigned short Ps[4][32 * 72];    // per-wave [q][k]

  const int bid = blockIdx.x;
  const int nb  = (bid & 7) * 96 + (bid >> 3);   // XCD swizzle (768 % 8 == 0)
  const int bh  = nb >> 4;
  const int qt  = nb & 15;
  const int tid = threadIdx.x;
  const int w    = tid >> 6;
  const int lane = tid & 63;
  const int g    = lane >> 4;
  const int l15  = lane & 15;

  const unsigned short* Qh  = qb + (size_t)bh * 2048 * 64;
  const unsigned short* Kh  = kb + (size_t)bh * 2048 * 64;
  const unsigned short* VTh = vt + (size_t)bh * 64 * 2048;

  const int qbase = qt * 128 + w * 32;

  bf8_t qfr[2][2];
#pragma unroll
  for (int qq = 0; qq < 2; ++qq)
#pragma unroll
    for (int s = 0; s < 2; ++s)
      qfr[qq][s] = *(const bf8_t*)(Qh + (size_t)(qbase + qq * 16 + l15) * 64 + s * 32 + g * 8);

  // staging geometry: each thread copies two 8-elem chunks per buffer
  const int srow0 = tid >> 3;          // 0..31
  const int srow1 = srow0 + 32;        // 32..63
  const int sc8   = tid & 7;
  const int soff  = sc8 * 8;
  const int sdst0 = srow0 * 64 + ((sc8 ^ (srow0 & 7)) * 8);
  const int sdst1 = srow1 * 64 + ((sc8 ^ (srow1 & 7)) * 8);

  // prologue: stage tile 0
  {
    bf8_t k0a = *(const bf8_t*)(Kh + srow0 * 64 + soff);
    bf8_t k0b = *(const bf8_t*)(Kh + srow1 * 64 + soff);
    bf8_t v0a = *(const bf8_t*)(VTh + srow0 * 2048 + soff);
    bf8_t v0b = *(const bf8_t*)(VTh + srow1 * 2048 + soff);
    *(bf8_t*)(&Ks[0][sdst0]) = k0a;
    *(bf8_t*)(&Ks[0][sdst1]) = k0b;
    *(bf8_t*)(&Vs[0][sdst0]) = v0a;
    *(bf8_t*)(&Vs[0][sdst1]) = v0b;
  }
  __syncthreads();

  float mref[2] = {-1e30f, -1e30f};
  float lsum[2] = {0.f, 0.f};
  const f4_t zf = {0.f, 0.f, 0.f, 0.f};
  f4_t accO[2][4];
#pragma unroll
  for (int qq = 0; qq < 2; ++qq)
#pragma unroll
    for (int nf = 0; nf < 4; ++nf) accO[qq][nf] = zf;

  unsigned short* const pw_base = &Ps[w][0];

  for (int t = 0; t < 32; ++t) {
    const int cur = t & 1, nxt = cur ^ 1;

    // issue next tile's loads early (latency hides under compute)
    bf8_t kn0, kn1, vn0, vn1;
    if (t < 31) {
      const unsigned short* Kt = Kh + (size_t)(t + 1) * 64 * 64;
      kn0 = *(const bf8_t*)(Kt + srow0 * 64 + soff);
      kn1 = *(const bf8_t*)(Kt + srow1 * 64 + soff);
      vn0 = *(const bf8_t*)(VTh + srow0 * 2048 + (t + 1) * 64 + soff);
      vn1 = *(const bf8_t*)(VTh + srow1 * 2048 + (t + 1) * 64 + soff);
    }

    // ---- S^T = K . Q^T ----
    const unsigned short* KsC = Ks[cur];
    bf8_t ka[4][2];
#pragma unroll
    for (int kf = 0; kf < 4; ++kf) {
      const int row = kf * 16 + l15;
#pragma unroll
      for (int s = 0; s < 2; ++s)
        ka[kf][s] = *(const bf8_t*)(KsC + row * 64 + (((s * 4 + g) ^ (row & 7)) * 8));
    }
    f4_t accS[4][2];
    __builtin_amdgcn_s_setprio(1);
#pragma unroll
    for (int kf = 0; kf < 4; ++kf)
#pragma unroll
      for (int qq = 0; qq < 2; ++qq) {
        f4_t a = zf;
        a = __builtin_amdgcn_mfma_f32_16x16x32_bf16(ka[kf][0], qfr[qq][0], a, 0, 0, 0);
        a = __builtin_amdgcn_mfma_f32_16x16x32_bf16(ka[kf][1], qfr[qq][1], a, 0, 0, 0);
        accS[kf][qq] = a;
      }
    __builtin_amdgcn_s_setprio(0);

    // ---- online softmax (exp2 domain), T13 defer-max ----
#pragma unroll
    for (int qq = 0; qq < 2; ++qq) {
      float rmax = accS[0][qq][0];
#pragma unroll
      for (int kf = 0; kf < 4; ++kf)
#pragma unroll
        for (int j = 0; j < 4; ++j)
          if (kf | j) rmax = fmaxf(rmax, accS[kf][qq][j]);
      rmax = fmaxf(rmax, __shfl_xor(rmax, 16));
      rmax = fmaxf(rmax, __shfl_xor(rmax, 32));
      if (!__all(rmax - mref[qq] <= 8.0f)) {
        const float mnew  = fmaxf(mref[qq], rmax);
        const float alpha = __builtin_amdgcn_exp2f(mref[qq] - mnew);
        mref[qq] = mnew;
        lsum[qq] *= alpha;
        f4_t av;
#pragma unroll
        for (int j = 0; j < 4; ++j) av[j] = __shfl(alpha, g * 4 + j);
#pragma unroll
        for (int nf = 0; nf < 4; ++nf) accO[qq][nf] *= av;
      }
      const float mr = mref[qq];
      float ps = 0.f;
      unsigned short* pw = pw_base + (qq * 16 + l15) * 72;
#pragma unroll
      for (int kf = 0; kf < 4; ++kf) {
        const float p0 = __builtin_amdgcn_exp2f(accS[kf][qq][0] - mr);
        const float p1 = __builtin_amdgcn_exp2f(accS[kf][qq][1] - mr);
        const float p2 = __builtin_amdgcn_exp2f(accS[kf][qq][2] - mr);
        const float p3 = __builtin_amdgcn_exp2f(accS[kf][qq][3] - mr);
        ps += (p0 + p1) + (p2 + p3);
        uint2 u = { cvt_pk_bf16(p0, p1), cvt_pk_bf16(p2, p3) };
        *(uint2*)(pw + kf * 16 + g * 4) = u;
      }
      ps += __shfl_xor(ps, 16);
      ps += __shfl_xor(ps, 32);
      lsum[qq] += ps;
    }

    // ---- PV ----
    const unsigned short* VsC = Vs[cur];
    bf8_t pa[2][2];
#pragma unroll
    for (int qq = 0; qq < 2; ++qq)
#pragma unroll
      for (int kk = 0; kk < 2; ++kk)
        pa[qq][kk] = *(const bf8_t*)(pw_base + (qq * 16 + l15) * 72 + kk * 32 + g * 8);
    __builtin_amdgcn_s_setprio(1);
#pragma unroll
    for (int kk = 0; kk < 2; ++kk)
#pragma unroll
      for (int nf = 0; nf < 4; ++nf) {
        const int d = nf * 16 + l15;
        bf8_t vfr = *(const bf8_t*)(VsC + d * 64 + (((kk * 4 + g) ^ (d & 7)) * 8));
#pragma unroll
        for (int qq = 0; qq < 2; ++qq)
          accO[qq][nf] = __builtin_amdgcn_mfma_f32_16x16x32_bf16(pa[qq][kk], vfr, accO[qq][nf], 0, 0, 0);
      }
    __builtin_amdgcn_s_setprio(0);

    // write next tile into the other buffer, then one barrier
    if (t < 31) {
      *(bf8_t*)(&Ks[nxt][sdst0]) = kn0;
      *(bf8_t*)(&Ks[nxt][sdst1]) = kn1;
      *(bf8_t*)(&Vs[nxt][sdst0]) = vn0;
      *(bf8_t*)(&Vs[nxt][sdst1]) = vn1;
    }
    __syncthreads();
  }

  // ---- finalize ----
  const int b = bh / 12, h = bh - (bh / 12) * 12;
#pragma unroll
  for (int qq = 0; qq < 2; ++qq) {
    const float rl = 1.0f / lsum[qq];
    f4_t lv;
#pragma unroll
    for (int j = 0; j < 4; ++j) lv[j] = __shfl(rl, g * 4 + j);
#pragma unroll
    for (int nf = 0; nf < 4; ++nf) {
#pragma unroll
      for (int j = 0; j < 4; ++j) {
        const int qrow = qbase + qq * 16 + g * 4 + j;
        out[((size_t)(b * 2048 + qrow)) * 768 + h * 64 + nf * 16 + l15] = accO[qq][nf][j] * lv[j];
      }
    }
  }
}

// ---------------------------------------------------------------------------
extern "C" void kernel_launch(void* const* d_in, const int* in_sizes, int n_in,
                              void* d_out, int out_size, void* d_ws, size_t ws_size,
                              hipStream_t stream) {
  (void)in_sizes; (void)n_in; (void)out_size; (void)ws_size;
  const float* Z = (const float*)d_in[0];
  const float* W = (const float*)d_in[1];
  float* out = (float*)d_out;

  unsigned short* qb = (unsigned short*)d_ws;                    // [48][2048][64]
  unsigned short* kb = qb + (size_t)48 * 2048 * 64;              // [48][2048][64]
  unsigned short* vt = kb + (size_t)48 * 2048 * 64;              // [48][64][2048]

  qkv_gemm_kernel<<<dim3(18, 64), 256, 0, stream>>>(Z, W, qb, kb, vt);
  attn_kernel<<<dim3(768), 256, 0, stream>>>(qb, kb, vt, out);
}